// Round 6
// baseline (11772.079 us; speedup 1.0000x reference)
//
#include <hip/hip_runtime.h>
#include <hip/hip_fp16.h>
#include <math.h>

#define S_LEN 2048
#define HD 512
#define G4 2048      // 4*HD gate rows
#define E_DIM 512
#define NTAG 12
#define TAG_START 10
#define TAG_STOP 11
#define NEGV -10000.0f

#define SENTI16 0x7E00u                   // fp16 NaN payload; tanh*sig never encodes to this
#define SENTI_PAIR 0x7E007E00u
#define H_UINTS (S_LEN * HD / 2)          // uints per direction (fp16 h)
#define POLL_BOUND (1 << 14)              // bounded escape: worst ~1 ms/step, never hangs

// ---------------- init: fill h buffer with fp16 sentinel, zero worker counters ----------------
__global__ void init_k(unsigned* __restrict__ p, int n, int* __restrict__ ctr)
{
    int i = blockIdx.x * blockDim.x + threadIdx.x;
    if (i < n) p[i] = SENTI_PAIR;
    if (i < 2) ctr[i] = 0;
}

// ---------------- X pre-GEMM: X[dir][t][row] = emb[t].Wih[row] + bih[row]+bhh[row] ----------------
#define BK 16
__global__ __launch_bounds__(256) void xgemm_k(
    const int* __restrict__ sent, const float* __restrict__ embed,
    const float* __restrict__ WihF, const float* __restrict__ WihB,
    const float* __restrict__ bihF, const float* __restrict__ bhhF,
    const float* __restrict__ bihB, const float* __restrict__ bhhB,
    float* __restrict__ Xf, float* __restrict__ Xb)
{
    const int dir = blockIdx.z;
    const float* __restrict__ Wih = dir ? WihB : WihF;
    const float* __restrict__ bih = dir ? bihB : bihF;
    const float* __restrict__ bhh = dir ? bhhB : bhhF;
    float* __restrict__ X = dir ? Xb : Xf;

    const int m0 = blockIdx.y * 64;   // t tile
    const int n0 = blockIdx.x * 64;   // gate-row tile
    const int tid = threadIdx.x;

    __shared__ float At[BK][68];      // transposed tiles: [k][row], pad 68
    __shared__ float Bt[BK][68];

    const int lr = tid >> 2;          // 0..63 staging row
    const int lc = (tid & 3) * 4;     // k sub-offset
    const float* __restrict__ arow = embed + (size_t)sent[m0 + lr] * E_DIM + lc;
    const float* __restrict__ brow = Wih + (size_t)(n0 + lr) * E_DIM + lc;

    const int tx = tid & 15, ty = tid >> 4;
    float acc[4][4] = {};

    for (int kt = 0; kt < E_DIM; kt += BK) {
        const float4 av = *(const float4*)(arow + kt);
        const float4 bv = *(const float4*)(brow + kt);
        __syncthreads();
        At[lc+0][lr] = av.x; At[lc+1][lr] = av.y; At[lc+2][lr] = av.z; At[lc+3][lr] = av.w;
        Bt[lc+0][lr] = bv.x; Bt[lc+1][lr] = bv.y; Bt[lc+2][lr] = bv.z; Bt[lc+3][lr] = bv.w;
        __syncthreads();
        #pragma unroll
        for (int kk = 0; kk < BK; ++kk) {
            const float4 a4 = *(const float4*)&At[kk][ty*4];
            const float4 b4 = *(const float4*)&Bt[kk][tx*4];
            const float a_[4] = {a4.x, a4.y, a4.z, a4.w};
            const float b_[4] = {b4.x, b4.y, b4.z, b4.w};
            #pragma unroll
            for (int i = 0; i < 4; ++i)
                #pragma unroll
                for (int j = 0; j < 4; ++j)
                    acc[i][j] += a_[i] * b_[j];
        }
    }
    float bias[4];
    #pragma unroll
    for (int j = 0; j < 4; ++j) {
        int col = n0 + tx*4 + j;
        bias[j] = bih[col] + bhh[col];
    }
    #pragma unroll
    for (int i = 0; i < 4; ++i) {
        int t = m0 + ty*4 + i;
        float4 o;
        o.x = acc[i][0] + bias[0];
        o.y = acc[i][1] + bias[1];
        o.z = acc[i][2] + bias[2];
        o.w = acc[i][3] + bias[3];
        *(float4*)(X + (size_t)t * G4 + n0 + tx*4) = o;
    }
}

// ---------------- recurrence: 64 worker blocks x 128 thr per direction ----------------
// Workers pinned per-XCD (fwd=XCD0, bwd=XCD1) via HW_REG_XCC_ID + atomic slot grab.
// Producer: dual store (plain -> local L2, sc0 sc1 -> MALL). Consumer: nt poll
// (no-allocate: re-probes L2 every iteration, falls to MALL on miss). Same-XCD =>
// L2-hit sync (~200cy); wrong placement => MALL sync (r1-r4 behavior). No hang modes.
#define NBW 64       // worker blocks per direction
#define UPBW 8       // hidden units per block (32 gate rows)
#define CHUNK 64     // h columns per lane

__global__ __attribute__((amdgpu_flat_work_group_size(128, 128), amdgpu_waves_per_eu(2)))
void lstm_rec(
    const float* __restrict__ WhhF, const float* __restrict__ WhhB,
    const float* __restrict__ Xf, const float* __restrict__ Xb,
    const float* __restrict__ h0, const float* __restrict__ c0,
    unsigned* __restrict__ H32,     // [dir][t][HD] fp16, viewed as uints
    int* __restrict__ ctr)
{
    // ---- XCD-verified worker self-selection (resident => co-resident forever) ----
    __shared__ int slot_s;
    if (threadIdx.x == 0) {
        unsigned xcc;
        asm volatile("s_getreg_b32 %0, hwreg(20)" : "=s"(xcc));   // HW_REG_XCC_ID
        xcc &= 0xF;
        int sl = -1;
        if (xcc == 0)      { int v = atomicAdd(&ctr[0], 1); if (v < NBW) sl = v; }
        else if (xcc == 1) { int v = atomicAdd(&ctr[1], 1); if (v < NBW) sl = NBW + v; }
        slot_s = sl;
    }
    __syncthreads();
    const int sl = slot_s;
    if (sl < 0) return;                   // not a worker
    const int dir = sl >> 6;
    const int b   = sl & 63;

    const float* __restrict__ Whh = dir ? WhhB : WhhF;
    const float* __restrict__ X   = dir ? Xb : Xf;
    const int dirbase = dir * H_UINTS;

    const int tid = threadIdx.x;       // 0..127
    const int k   = tid & 7;           // column chunk
    const int rp  = tid >> 3;          // 0..15 row-pair
    const int l   = tid & 63;
    const int wv  = tid >> 6;          // wave 0/1
    const int ra  = 2*rp, rb = 2*rp + 1;              // local gate rows [0,32)
    const int grow_a = (ra & 3)*HD + b*UPBW + (ra >> 2);
    const int grow_b = (rb & 3)*HD + b*UPBW + (rb >> 2);
    const int unit   = rp >> 1;                        // 0..7 local unit
    const int gunit  = b*UPBW + unit;
    const bool oddrp = (rp & 1) != 0;                  // odd: rows are (g,o); even: (i,f)

    // 2 rows x 64 cols of Whh per lane, as 32 NAMED float4s, pinned opaque (r3 mechanism)
    const float4* wpa = (const float4*)(Whh + (size_t)grow_a * HD + k * CHUNK);
    const float4* wpb = (const float4*)(Whh + (size_t)grow_b * HD + k * CHUNK);
#define WDECL(i) float4 wa##i = wpa[i]; float4 wb##i = wpb[i];
    WDECL(0)  WDECL(1)  WDECL(2)  WDECL(3)
    WDECL(4)  WDECL(5)  WDECL(6)  WDECL(7)
    WDECL(8)  WDECL(9)  WDECL(10) WDECL(11)
    WDECL(12) WDECL(13) WDECL(14) WDECL(15)
#define WPIN(i) asm volatile("" : "+v"(wa##i.x), "+v"(wa##i.y), "+v"(wa##i.z), "+v"(wa##i.w), \
                                  "+v"(wb##i.x), "+v"(wb##i.y), "+v"(wb##i.z), "+v"(wb##i.w));
    WPIN(0)  WPIN(1)  WPIN(2)  WPIN(3)
    WPIN(4)  WPIN(5)  WPIN(6)  WPIN(7)
    WPIN(8)  WPIN(9)  WPIN(10) WPIN(11)
    WPIN(12) WPIN(13) WPIN(14) WPIN(15)

    __shared__ float hlds[2][8 * 68];  // double-buffered h row, chunk stride 68 (conflict-free)

    float c = c0[dir*HD + gunit];      // meaningful on cell lanes (k==0, rp even)

    // prefetch X for step 0 (nt: keep the sync L2 clean)
    float xa = 0.f, xb = 0.f;
    {
        const int t0 = dir ? (S_LEN-1) : 0;
        if (k == 0) {
            xa = __builtin_nontemporal_load(&X[(size_t)t0 * G4 + grow_a]);
            xb = __builtin_nontemporal_load(&X[(size_t)t0 * G4 + grow_b]);
        }
    }

    for (int s = 0; s < S_LEN; ++s) {
        const int t_io = dir ? (S_LEN-1-s) : s;
        float* __restrict__ hl = hlds[s & 1];

        // ---- stage h[t-1]: all 128 lanes poll 8B (4 fp16) each ----
        float4 hw;
        if (s == 0) {
            hw = ((const float4*)(h0 + dir*HD))[tid];
        } else {
            const int prev = dir ? (t_io+1) : (t_io-1);
            const unsigned long long* src =
                (const unsigned long long*)(H32 + dirbase + prev*(HD/2)) + tid;
            unsigned long long v;
            int it = 0;
            for (;;) {
                // nt = no-allocate: probes L2 fresh every time, no stale line possible
                asm volatile("global_load_dwordx2 %0, %1, off nt\n\t"
                             "s_waitcnt vmcnt(0)"
                             : "=v"(v) : "v"(src) : "memory");
                if ((unsigned)v != SENTI_PAIR && (unsigned)(v >> 32) != SENTI_PAIR) break;
                if (++it >= POLL_BOUND) break;   // fail-visible escape
            }
            const float2 f0 = __half22float2(*(const __half2*)&v);
            const float2 f1 = __half22float2(((const __half2*)&v)[1]);
            hw.x = f0.x; hw.y = f0.y; hw.z = f1.x; hw.w = f1.y;
        }
        {
            const int ch  = tid >> 4;            // 0..7
            const int off = (tid * 4) & 63;
            *(float4*)(hl + ch*68 + off) = hw;
        }
        __syncthreads();   // single barrier per step (double-buffered hlds)

        // prefetch next step's X (hides under dot)
        float xan = 0.f, xbn = 0.f;
        if (k == 0 && s + 1 < S_LEN) {
            const int t_nx = dir ? (t_io-1) : (t_io+1);
            xan = __builtin_nontemporal_load(&X[(size_t)t_nx * G4 + grow_a]);
            xbn = __builtin_nontemporal_load(&X[(size_t)t_nx * G4 + grow_b]);
        }

        // ---- dot: 2 rows x 64 cols per lane (h chunk broadcast from LDS) ----
        float aa0=0.f, aa1=0.f, aa2=0.f, aa3=0.f;
        float ab0=0.f, ab1=0.f, ab2=0.f, ab3=0.f;
        const float* __restrict__ hp = &hl[k * 68];
#define WDOT(i) { const float4 hv = *(const float4*)(hp + 4*(i)); \
        aa0 += wa##i.x*hv.x; aa1 += wa##i.y*hv.y; aa2 += wa##i.z*hv.z; aa3 += wa##i.w*hv.w; \
        ab0 += wb##i.x*hv.x; ab1 += wb##i.y*hv.y; ab2 += wb##i.z*hv.z; ab3 += wb##i.w*hv.w; }
        WDOT(0)  WDOT(1)  WDOT(2)  WDOT(3)
        WDOT(4)  WDOT(5)  WDOT(6)  WDOT(7)
        WDOT(8)  WDOT(9)  WDOT(10) WDOT(11)
        WDOT(12) WDOT(13) WDOT(14) WDOT(15)
        float sa = (aa0 + aa1) + (aa2 + aa3);
        float sb = (ab0 + ab1) + (ab2 + ab3);

        // reduce across the 8 chunk lanes (k = lane bits 0-2)
        sa += __shfl_xor(sa, 1); sa += __shfl_xor(sa, 2); sa += __shfl_xor(sa, 4);
        sb += __shfl_xor(sb, 1); sb += __shfl_xor(sb, 2); sb += __shfl_xor(sb, 4);
        const float pre_a = sa + xa;     // valid on k==0 lanes
        const float pre_b = sb + xb;

        // activations: even rp -> (i,f) both sigmoid; odd rp -> (g tanh, o sigmoid)
        const float ya    = oddrp ? 2.f*pre_a : pre_a;
        const float sga   = 1.f / (1.f + __expf(-ya));
        const float act_a = oddrp ? 2.f*sga - 1.f : sga;
        const float act_b = 1.f / (1.f + __expf(-pre_b));

        // gather (g,o) from the rp-odd partner lane (lane bit 3)
        const float a_g = __shfl_xor(act_a, 8);
        const float a_o = __shfl_xor(act_b, 8);

        // cell + h (meaningful on k==0 & rp even lanes: l % 16 == 0)
        c = act_b*c + act_a*a_g;
        const float th = 2.f / (1.f + __expf(-2.f*c)) - 1.f;
        const float h  = a_o * th;

        // pack 4 units of this wave into one 8B packet, dual-store (L2 + MALL)
        const float h2 = __shfl_xor(h, 16);   // partner unit
        const unsigned ph =
            (unsigned)__half_as_ushort(__float2half_rn(h)) |
            ((unsigned)__half_as_ushort(__float2half_rn(h2)) << 16);
        const unsigned ph32 = __shfl_xor(ph, 32);
        if (l == 0) {
            const unsigned long long pv = (unsigned long long)ph |
                                          ((unsigned long long)ph32 << 32);
            unsigned* dst = H32 + dirbase + t_io*(HD/2) + b*4 + wv*2;
            asm volatile("global_store_dwordx2 %0, %1, off\n\t"
                         "global_store_dwordx2 %0, %1, off sc0 sc1"
                         :: "v"(dst), "v"(pv) : "memory");
        }
        xa = xan; xb = xbn;
    }
}

// ---------------- feats: [hf,hb] @ Wout.T + bout (h in fp16) ----------------
__global__ __launch_bounds__(256) void feats_k(
    const __half* __restrict__ H,
    const float* __restrict__ Wout, const float* __restrict__ bout,
    float* __restrict__ feats)
{
    int idx = blockIdx.x * blockDim.x + threadIdx.x;
    if (idx >= S_LEN * NTAG) return;
    int t = idx / NTAG, tag = idx - t*NTAG;
    const float* __restrict__ wf = Wout + (size_t)tag * (2*HD);
    const __half2* __restrict__ hf2 = (const __half2*)(H + (size_t)t * HD);
    const __half2* __restrict__ hb2 = (const __half2*)(H + (size_t)S_LEN*HD + (size_t)t * HD);
    float acc = bout[tag];
    for (int i = 0; i < HD; i += 4) {
        float2 f0 = __half22float2(hf2[(i>>1)]);
        float2 f1 = __half22float2(hf2[(i>>1)+1]);
        float4 w4 = *(const float4*)(wf + i);
        acc += f0.x*w4.x + f0.y*w4.y + f1.x*w4.z + f1.y*w4.w;
    }
    for (int i = 0; i < HD; i += 4) {
        float2 f0 = __half22float2(hb2[(i>>1)]);
        float2 f1 = __half22float2(hb2[(i>>1)+1]);
        float4 w4 = *(const float4*)(wf + HD + i);
        acc += f0.x*w4.x + f0.y*w4.y + f1.x*w4.z + f1.y*w4.w;
    }
    feats[idx] = acc;
}

// ---------------- Viterbi forward + backtrace, single block ----------------
__global__ __launch_bounds__(256, 1) void viterbi_k(
    const float* __restrict__ feats, const float* __restrict__ trans,
    float* __restrict__ out)
{
    __shared__ float fl[S_LEN * NTAG];           // 96 KB
    __shared__ unsigned char bpl[S_LEN * NTAG];  // 24 KB
    {
        const float4* src = (const float4*)feats;
        float4* dst = (float4*)fl;
        for (int i = threadIdx.x; i < S_LEN*NTAG/4; i += 256) dst[i] = src[i];
    }
    __syncthreads();
    if (threadIdx.x < 64) {
        const int ln = threadIdx.x;
        if (ln < NTAG) {
            float tr[NTAG];
            #pragma unroll
            for (int p = 0; p < NTAG; ++p) tr[p] = trans[ln*NTAG + p];
            float fv = (ln == TAG_START) ? 0.f : NEGV;
            for (int t = 0; t < S_LEN; ++t) {
                float best = -3.4e38f; int arg = 0;
                #pragma unroll
                for (int p = 0; p < NTAG; ++p) {
                    float sc = __shfl(fv, p) + tr[p];
                    if (sc > best) { best = sc; arg = p; }   // strict > = first-max (np argmax)
                }
                bpl[t*NTAG + ln] = (unsigned char)arg;
                fv = best + fl[t*NTAG + ln];
            }
            float tsc = fv + trans[TAG_STOP*NTAG + ln];
            float bestt = -3.4e38f; int argt = 0;
            #pragma unroll
            for (int p = 0; p < NTAG; ++p) {
                float v = __shfl(tsc, p);
                if (v > bestt) { bestt = v; argt = p; }
            }
            if (ln == 0) {
                out[0] = bestt;
                int tag = argt;
                for (int t = S_LEN-1; t >= 0; --t) {
                    out[1+t] = (float)tag;
                    tag = bpl[t*NTAG + tag];
                }
            }
        }
    }
}

// ---------------- launch ----------------
extern "C" void kernel_launch(void* const* d_in, const int* in_sizes, int n_in,
                              void* d_out, int out_size, void* d_ws, size_t ws_size,
                              hipStream_t stream)
{
    const int*   sent  = (const int*)d_in[0];
    const float* embed = (const float*)d_in[1];
    const float* WihF  = (const float*)d_in[2];
    const float* WhhF  = (const float*)d_in[3];
    const float* bihF  = (const float*)d_in[4];
    const float* bhhF  = (const float*)d_in[5];
    const float* WihB  = (const float*)d_in[6];
    const float* WhhB  = (const float*)d_in[7];
    const float* bihB  = (const float*)d_in[8];
    const float* bhhB  = (const float*)d_in[9];
    const float* h0    = (const float*)d_in[10];
    const float* c0    = (const float*)d_in[11];
    const float* Wout  = (const float*)d_in[12];
    const float* bout  = (const float*)d_in[13];
    const float* trans = (const float*)d_in[14];
    float* out = (float*)d_out;

    float* ws = (float*)d_ws;
    float* Xf = ws;                                         // 16 MB
    float* Xb = Xf + (size_t)S_LEN * G4;                    // 16 MB
    unsigned* H32 = (unsigned*)(Xb + (size_t)S_LEN * G4);   // 4 MB: [2 dir][t][HD] fp16
    float* feats = (float*)(H32 + (size_t)2 * H_UINTS);     // 96 KB
    int* ctr = (int*)(feats + (size_t)S_LEN * NTAG);        // 2 ints

    // 1) sentinel-fill the h buffer + zero worker counters
    {
        int n = 2 * H_UINTS;
        init_k<<<(n + 255)/256, 256, 0, stream>>>(H32, n, ctr);
    }
    // 2) X pre-GEMM for both directions
    {
        dim3 grid(G4/64, S_LEN/64, 2);
        xgemm_k<<<grid, 256, 0, stream>>>(sent, embed, WihF, WihB,
                                          bihF, bhhF, bihB, bhhB, Xf, Xb);
    }
    // 3) recurrence: 2048 candidates; 64 XCD0-verified (fwd) + 64 XCD1-verified (bwd) work
    lstm_rec<<<2048, 128, 0, stream>>>(WhhF, WhhB, Xf, Xb, h0, c0, H32, ctr);
    // 4) emission features
    {
        int n = S_LEN * NTAG;
        feats_k<<<(n + 255)/256, 256, 0, stream>>>((const __half*)H32, Wout, bout, feats);
    }
    // 5) Viterbi decode
    viterbi_k<<<1, 256, 0, stream>>>(feats, trans, out);
}

// Round 7
// 10540.719 us; speedup vs baseline: 1.1168x; 1.1168x over previous
//
#include <hip/hip_runtime.h>
#include <math.h>

#define S_LEN 2048
#define HD 512
#define G4 2048      // 4*HD gate rows
#define E_DIM 512
#define NTAG 12
#define TAG_START 10
#define TAG_STOP 11
#define NEGV -10000.0f

// byte-repeating sentinel (memset 0x7F): fp32 3.39e38 — |h| < 1 can never equal it
#define SENT 0x7F7F7F7Fu

// ---------------- X pre-GEMM: X[dir][t][row] = emb[t].Wih[row] + bih[row]+bhh[row] ----------------
#define BK 16
__global__ __launch_bounds__(256) void xgemm_k(
    const int* __restrict__ sent, const float* __restrict__ embed,
    const float* __restrict__ WihF, const float* __restrict__ WihB,
    const float* __restrict__ bihF, const float* __restrict__ bhhF,
    const float* __restrict__ bihB, const float* __restrict__ bhhB,
    float* __restrict__ Xf, float* __restrict__ Xb)
{
    const int dir = blockIdx.z;
    const float* __restrict__ Wih = dir ? WihB : WihF;
    const float* __restrict__ bih = dir ? bihB : bihF;
    const float* __restrict__ bhh = dir ? bhhB : bhhF;
    float* __restrict__ X = dir ? Xb : Xf;

    const int m0 = blockIdx.y * 64;   // t tile
    const int n0 = blockIdx.x * 64;   // gate-row tile
    const int tid = threadIdx.x;

    __shared__ float At[BK][68];      // transposed tiles: [k][row], pad 68
    __shared__ float Bt[BK][68];

    const int lr = tid >> 2;          // 0..63 staging row
    const int lc = (tid & 3) * 4;     // k sub-offset
    const float* __restrict__ arow = embed + (size_t)sent[m0 + lr] * E_DIM + lc;
    const float* __restrict__ brow = Wih + (size_t)(n0 + lr) * E_DIM + lc;

    const int tx = tid & 15, ty = tid >> 4;
    float acc[4][4] = {};

    for (int kt = 0; kt < E_DIM; kt += BK) {
        const float4 av = *(const float4*)(arow + kt);
        const float4 bv = *(const float4*)(brow + kt);
        __syncthreads();
        At[lc+0][lr] = av.x; At[lc+1][lr] = av.y; At[lc+2][lr] = av.z; At[lc+3][lr] = av.w;
        Bt[lc+0][lr] = bv.x; Bt[lc+1][lr] = bv.y; Bt[lc+2][lr] = bv.z; Bt[lc+3][lr] = bv.w;
        __syncthreads();
        #pragma unroll
        for (int kk = 0; kk < BK; ++kk) {
            const float4 a4 = *(const float4*)&At[kk][ty*4];
            const float4 b4 = *(const float4*)&Bt[kk][tx*4];
            const float a_[4] = {a4.x, a4.y, a4.z, a4.w};
            const float b_[4] = {b4.x, b4.y, b4.z, b4.w};
            #pragma unroll
            for (int i = 0; i < 4; ++i)
                #pragma unroll
                for (int j = 0; j < 4; ++j)
                    acc[i][j] += a_[i] * b_[j];
        }
    }
    float bias[4];
    #pragma unroll
    for (int j = 0; j < 4; ++j) {
        int col = n0 + tx*4 + j;
        bias[j] = bih[col] + bhh[col];
    }
    #pragma unroll
    for (int i = 0; i < 4; ++i) {
        int t = m0 + ty*4 + i;
        float4 o;
        o.x = acc[i][0] + bias[0];
        o.y = acc[i][1] + bias[1];
        o.z = acc[i][2] + bias[2];
        o.w = acc[i][3] + bias[3];
        *(float4*)(X + (size_t)t * G4 + n0 + tx*4) = o;
    }
}

// ---------------- recurrence: 128 blocks, EACH handling a fwd slice AND a bwd slice ----------------
// Per round: fwd step s then bwd step (2047-s). Each chain's store->poll RT hides under the
// other chain's half-round. Polls are issued speculatively a half-round before their check.
// Protocol = r1's proven primitives: relaxed agent atomics, fp32 h, 4B per-unit stores.
__global__ __launch_bounds__(256) void lstm_rec(
    const float* __restrict__ WhhF, const float* __restrict__ WhhB,
    const float* __restrict__ Xf, const float* __restrict__ Xb,
    const float* __restrict__ h0, const float* __restrict__ c0,
    unsigned* __restrict__ Hf, unsigned* __restrict__ Hb)
{
    const int b   = blockIdx.x;        // 0..127
    const int tid = threadIdx.x;       // 0..255
    const int L   = tid & 63;
    const int wv  = tid >> 6;          // wave = local unit 0..3
    const int row = tid >> 4;          // 0..15 = unit*4 + gate
    const int seg = tid & 15;          // 32-col segment
    const int u   = row >> 2;
    const int g   = row & 3;           // gate (i,f,g,o)
    const int ubase = b * 4;           // this block's 4 units (same slice both dirs)
    const int grow  = g * HD + ubase + u;   // global gate row in [0,2048)

    // weights: 8 float4 per direction per thread, pinned in VGPRs (r3 mechanism)
    const float4* wfp = (const float4*)(WhhF + (size_t)grow * HD + seg * 32);
    const float4* wbp = (const float4*)(WhhB + (size_t)grow * HD + seg * 32);
#define WDECLFB(i) float4 wf##i = wfp[i]; float4 wb##i = wbp[i];
    WDECLFB(0) WDECLFB(1) WDECLFB(2) WDECLFB(3)
    WDECLFB(4) WDECLFB(5) WDECLFB(6) WDECLFB(7)
#define WPINFB(i) asm volatile("" : "+v"(wf##i.x), "+v"(wf##i.y), "+v"(wf##i.z), "+v"(wf##i.w), \
                                    "+v"(wb##i.x), "+v"(wb##i.y), "+v"(wb##i.z), "+v"(wb##i.w));
    WPINFB(0) WPINFB(1) WPINFB(2) WPINFB(3)
    WPINFB(4) WPINFB(5) WPINFB(6) WPINFB(7)

    __shared__ float hfl[512];
    __shared__ float hbl[512];

    float cf = 0.f, cb = 0.f;
    if (L == 0) { cf = c0[ubase + wv]; cb = c0[HD + ubase + wv]; }

    // X prefetch for round 0
    float xf = 0.f, xb = 0.f;
    if (seg == 0) {
        xf = Xf[(size_t)0 * G4 + grow];
        xb = Xb[(size_t)(S_LEN-1) * G4 + grow];
    }

    unsigned long long vf = 0, vb = 0;   // speculative poll snapshots

    for (int s = 0; s < S_LEN; ++s) {
        const int tf = s;
        const int tb = S_LEN - 1 - s;

        // ---- stage fwd h[tf-1]: verify speculative vf (issued last round), retry if stale ----
        if (s == 0) {
            const float2 hv = ((const float2*)h0)[tid];
            *(float2*)(hfl + tid*2) = hv;
        } else {
            const unsigned long long* srcf =
                (const unsigned long long*)(Hf + (size_t)(tf-1)*HD) + tid;
            int it = 0;
            while (((unsigned)vf == SENT || (unsigned)(vf>>32) == SENT) && it < 4096) {
                vf = __hip_atomic_load(srcf, __ATOMIC_RELAXED, __HIP_MEMORY_SCOPE_AGENT);
                ++it;
            }
            hfl[tid*2]   = __uint_as_float((unsigned)vf);
            hfl[tid*2+1] = __uint_as_float((unsigned)(vf >> 32));
        }
        __syncthreads();                       // BAR1

        // ---- speculative issue: this round's bwd row (stored ~3/4 round ago) ----
        if (s > 0)
            vb = __hip_atomic_load(
                (const unsigned long long*)(Hb + (size_t)(tb+1)*HD) + tid,
                __ATOMIC_RELAXED, __HIP_MEMORY_SCOPE_AGENT);

        // prefetch next round's X (hides under this round's compute)
        float xfn = 0.f, xbn = 0.f;
        if (seg == 0 && s + 1 < S_LEN) {
            xfn = Xf[(size_t)(tf+1) * G4 + grow];
            xbn = Xb[(size_t)(tb-1) * G4 + grow];
        }

        // ---- fwd dot + cell + store ----
        {
            float a0=0.f, a1=0.f, a2=0.f, a3=0.f;
            const float* __restrict__ hp = hfl + seg*32;
#define FDOT(i) { const float4 hv = *(const float4*)(hp + 4*(i)); \
            a0 += wf##i.x*hv.x; a1 += wf##i.y*hv.y; a2 += wf##i.z*hv.z; a3 += wf##i.w*hv.w; }
            FDOT(0) FDOT(1) FDOT(2) FDOT(3) FDOT(4) FDOT(5) FDOT(6) FDOT(7)
            float acc = (a0+a1)+(a2+a3);
            acc += __shfl_xor(acc, 1); acc += __shfl_xor(acc, 2);
            acc += __shfl_xor(acc, 4); acc += __shfl_xor(acc, 8);
            const float pre = acc + xf;              // valid at seg==0
            const float yy  = (g == 2) ? 2.f*pre : pre;
            const float sg_ = 1.f / (1.f + __expf(-yy));
            const float act = (g == 2) ? 2.f*sg_ - 1.f : sg_;
            const float ai = __shfl(act, 0);         // gates live at lanes 0,16,32,48
            const float af = __shfl(act, 16);
            const float ag = __shfl(act, 32);
            const float ao = __shfl(act, 48);
            if (L == 0) {
                cf = af*cf + ai*ag;
                const float th = 2.f / (1.f + __expf(-2.f*cf)) - 1.f;
                const float h  = ao * th;
                __hip_atomic_store(Hf + (size_t)tf*HD + ubase + wv, __float_as_uint(h),
                                   __ATOMIC_RELAXED, __HIP_MEMORY_SCOPE_AGENT);
            }
        }

        // ---- speculative issue: next round's fwd row (just stored by all blocks) ----
        if (s + 1 < S_LEN)
            vf = __hip_atomic_load(
                (const unsigned long long*)(Hf + (size_t)tf*HD) + tid,
                __ATOMIC_RELAXED, __HIP_MEMORY_SCOPE_AGENT);

        // ---- stage bwd h[tb+1]: verify speculative vb, retry if stale ----
        if (s == 0) {
            const float2 hv = ((const float2*)(h0 + HD))[tid];
            *(float2*)(hbl + tid*2) = hv;
        } else {
            const unsigned long long* srcb =
                (const unsigned long long*)(Hb + (size_t)(tb+1)*HD) + tid;
            int it = 0;
            while (((unsigned)vb == SENT || (unsigned)(vb>>32) == SENT) && it < 4096) {
                vb = __hip_atomic_load(srcb, __ATOMIC_RELAXED, __HIP_MEMORY_SCOPE_AGENT);
                ++it;
            }
            hbl[tid*2]   = __uint_as_float((unsigned)vb);
            hbl[tid*2+1] = __uint_as_float((unsigned)(vb >> 32));
        }
        __syncthreads();                       // BAR2

        // ---- bwd dot + cell + store ----
        {
            float a0=0.f, a1=0.f, a2=0.f, a3=0.f;
            const float* __restrict__ hp = hbl + seg*32;
#define BDOT(i) { const float4 hv = *(const float4*)(hp + 4*(i)); \
            a0 += wb##i.x*hv.x; a1 += wb##i.y*hv.y; a2 += wb##i.z*hv.z; a3 += wb##i.w*hv.w; }
            BDOT(0) BDOT(1) BDOT(2) BDOT(3) BDOT(4) BDOT(5) BDOT(6) BDOT(7)
            float acc = (a0+a1)+(a2+a3);
            acc += __shfl_xor(acc, 1); acc += __shfl_xor(acc, 2);
            acc += __shfl_xor(acc, 4); acc += __shfl_xor(acc, 8);
            const float pre = acc + xb;
            const float yy  = (g == 2) ? 2.f*pre : pre;
            const float sg_ = 1.f / (1.f + __expf(-yy));
            const float act = (g == 2) ? 2.f*sg_ - 1.f : sg_;
            const float ai = __shfl(act, 0);
            const float af = __shfl(act, 16);
            const float ag = __shfl(act, 32);
            const float ao = __shfl(act, 48);
            if (L == 0) {
                cb = af*cb + ai*ag;
                const float th = 2.f / (1.f + __expf(-2.f*cb)) - 1.f;
                const float h  = ao * th;
                __hip_atomic_store(Hb + (size_t)tb*HD + ubase + wv, __float_as_uint(h),
                                   __ATOMIC_RELAXED, __HIP_MEMORY_SCOPE_AGENT);
            }
        }

        xf = xfn; xb = xbn;
    }
}

// ---------------- feats: [hf,hb] @ Wout.T + bout ----------------
__global__ __launch_bounds__(256) void feats_k(
    const float* __restrict__ hf, const float* __restrict__ hb,
    const float* __restrict__ Wout, const float* __restrict__ bout,
    float* __restrict__ feats)
{
    int idx = blockIdx.x * blockDim.x + threadIdx.x;
    if (idx >= S_LEN * NTAG) return;
    int t = idx / NTAG, tag = idx - t*NTAG;
    const float* __restrict__ wf  = Wout + (size_t)tag * (2*HD);
    const float* __restrict__ ha  = hf + (size_t)t * HD;
    const float* __restrict__ hbr = hb + (size_t)t * HD;
    float a0=0.f, a1=0.f, a2=0.f, a3=0.f;
    for (int i = 0; i < HD; i += 4) {
        float4 h4 = *(const float4*)(ha + i);
        float4 w4 = *(const float4*)(wf + i);
        a0 += h4.x*w4.x; a1 += h4.y*w4.y; a2 += h4.z*w4.z; a3 += h4.w*w4.w;
    }
    for (int i = 0; i < HD; i += 4) {
        float4 h4 = *(const float4*)(hbr + i);
        float4 w4 = *(const float4*)(wf + HD + i);
        a0 += h4.x*w4.x; a1 += h4.y*w4.y; a2 += h4.z*w4.z; a3 += h4.w*w4.w;
    }
    feats[idx] = a0+a1+a2+a3 + bout[tag];
}

// ---------------- Viterbi forward + backtrace, single block ----------------
__global__ __launch_bounds__(256, 1) void viterbi_k(
    const float* __restrict__ feats, const float* __restrict__ trans,
    float* __restrict__ out)
{
    __shared__ float fl[S_LEN * NTAG];           // 96 KB
    __shared__ unsigned char bpl[S_LEN * NTAG];  // 24 KB
    {
        const float4* src = (const float4*)feats;
        float4* dst = (float4*)fl;
        for (int i = threadIdx.x; i < S_LEN*NTAG/4; i += 256) dst[i] = src[i];
    }
    __syncthreads();
    if (threadIdx.x < 64) {
        const int ln = threadIdx.x;
        if (ln < NTAG) {
            float tr[NTAG];
            #pragma unroll
            for (int p = 0; p < NTAG; ++p) tr[p] = trans[ln*NTAG + p];
            float fv = (ln == TAG_START) ? 0.f : NEGV;
            for (int t = 0; t < S_LEN; ++t) {
                float best = -3.4e38f; int arg = 0;
                #pragma unroll
                for (int p = 0; p < NTAG; ++p) {
                    float sc = __shfl(fv, p) + tr[p];
                    if (sc > best) { best = sc; arg = p; }   // strict > = first-max (np argmax)
                }
                bpl[t*NTAG + ln] = (unsigned char)arg;
                fv = best + fl[t*NTAG + ln];
            }
            float tsc = fv + trans[TAG_STOP*NTAG + ln];
            float bestt = -3.4e38f; int argt = 0;
            #pragma unroll
            for (int p = 0; p < NTAG; ++p) {
                float v = __shfl(tsc, p);
                if (v > bestt) { bestt = v; argt = p; }
            }
            if (ln == 0) {
                out[0] = bestt;
                int tag = argt;
                for (int t = S_LEN-1; t >= 0; --t) {
                    out[1+t] = (float)tag;
                    tag = bpl[t*NTAG + tag];
                }
            }
        }
    }
}

// ---------------- launch ----------------
extern "C" void kernel_launch(void* const* d_in, const int* in_sizes, int n_in,
                              void* d_out, int out_size, void* d_ws, size_t ws_size,
                              hipStream_t stream)
{
    const int*   sent  = (const int*)d_in[0];
    const float* embed = (const float*)d_in[1];
    const float* WihF  = (const float*)d_in[2];
    const float* WhhF  = (const float*)d_in[3];
    const float* bihF  = (const float*)d_in[4];
    const float* bhhF  = (const float*)d_in[5];
    const float* WihB  = (const float*)d_in[6];
    const float* WhhB  = (const float*)d_in[7];
    const float* bihB  = (const float*)d_in[8];
    const float* bhhB  = (const float*)d_in[9];
    const float* h0    = (const float*)d_in[10];
    const float* c0    = (const float*)d_in[11];
    const float* Wout  = (const float*)d_in[12];
    const float* bout  = (const float*)d_in[13];
    const float* trans = (const float*)d_in[14];
    float* out = (float*)d_out;

    float* ws = (float*)d_ws;
    float* Xf = ws;                                   // 16 MB
    float* Xb = Xf + (size_t)S_LEN * G4;              // 16 MB
    float* hf = Xb + (size_t)S_LEN * G4;              // 4 MB
    float* hb = hf + (size_t)S_LEN * HD;              // 4 MB
    float* feats = hb + (size_t)S_LEN * HD;           // 96 KB

    // 1) sentinel-fill both h buffers (byte pattern 0x7F -> fp32 3.39e38)
    hipMemsetAsync(hf, 0x7F, (size_t)2 * S_LEN * HD * sizeof(float), stream);
    // 2) X pre-GEMM for both directions
    {
        dim3 grid(G4/64, S_LEN/64, 2);
        xgemm_k<<<grid, 256, 0, stream>>>(sent, embed, WihF, WihB,
                                          bihF, bhhF, bihB, bhhB, Xf, Xb);
    }
    // 3) interleaved bidirectional recurrence: 128 blocks, each owns 4 fwd + 4 bwd units
    lstm_rec<<<128, 256, 0, stream>>>(WhhF, WhhB, Xf, Xb, h0, c0,
                                      (unsigned*)hf, (unsigned*)hb);
    // 4) emission features
    {
        int n = S_LEN * NTAG;
        feats_k<<<(n + 255)/256, 256, 0, stream>>>(hf, hb, Wout, bout, feats);
    }
    // 5) Viterbi decode
    viterbi_k<<<1, 256, 0, stream>>>(feats, trans, out);
}